// Round 1
// baseline (1297.119 us; speedup 1.0000x reference)
//
#include <hip/hip_runtime.h>

#define NV 400000
#define KOFF 27
#define CD 64
#define DD 128
#define HH 128
#define WW 128
#define TABN (2*DD*HH*WW)
#define EPSV 1e-5f

typedef _Float16 f16;
typedef _Float16 f16x8 __attribute__((ext_vector_type(8)));
typedef float f32x16 __attribute__((ext_vector_type(16)));

// ---- workspace layout (bytes) ----
// nbr:  27*N*4          = 43,200,000
// x1 :  N*64*2          = 51,200,000
// x2 :  N*64*2          = 51,200,000   (table overlaps x2: table dead before x2 written)
// w2t,w3t: 27*64*64*2 each = 221,184
// zero row: 128
#define OFF_NBR   0ull
#define OFF_X1    43200000ull
#define OFF_X2    94400000ull
#define OFF_TAB   94400000ull
#define OFF_W2T   145600000ull
#define OFF_W3T   145821184ull
#define OFF_ZERO  146042368ull

#define GLDS16(gp, lp) __builtin_amdgcn_global_load_lds( \
    (__attribute__((address_space(1))) void*)(gp), \
    (__attribute__((address_space(3))) void*)(lp), 16, 0, 0)

// ---- init: table = -1, transpose+cast weights to f16 [k][cout][cin], zero row ----
__global__ void k_init(const float* __restrict__ w2, const float* __restrict__ w3,
                       int* __restrict__ tab, f16* __restrict__ w2t,
                       f16* __restrict__ w3t, f16* __restrict__ zrow) {
    int t = blockIdx.x * 256 + threadIdx.x;           // grid: 4096*256 = 1,048,576
    int4* tv = (int4*)tab;
    if (t < TABN / 4) tv[t] = make_int4(-1, -1, -1, -1);
    if (t < KOFF * CD * CD) {                          // 110592
        int k = t >> 12, r = t & 4095, c = r >> 6, ci = r & 63;
        w2t[t] = (f16)w2[(k << 12) + (ci << 6) + c];
        w3t[t] = (f16)w3[(k << 12) + (ci << 6) + c];
    }
    if (t < CD) zrow[t] = (f16)0.f;
}

__global__ void k_scatter(const int4* __restrict__ coords, int* __restrict__ tab) {
    int i = blockIdx.x * 256 + threadIdx.x;
    if (i >= NV) return;
    int4 c = coords[i];  // (b,z,y,x)
    int flat = ((c.x * DD + c.y) * HH + c.z) * WW + c.w;
    tab[flat] = i;
}

__global__ void k_nbr(const int4* __restrict__ coords, const int* __restrict__ tab,
                      int* __restrict__ nbr) {
    int i = blockIdx.x * 256 + threadIdx.x;
    if (i >= NV) return;
    int4 c = coords[i];
    int k = 0;
    #pragma unroll
    for (int dz = -1; dz <= 1; dz++)
    #pragma unroll
    for (int dy = -1; dy <= 1; dy++)
    #pragma unroll
    for (int dx = -1; dx <= 1; dx++) {
        int z = c.y + dz, y = c.z + dy, x = c.w + dx;
        int idx = -1;
        if (z >= 0 && z < DD && y >= 0 && y < HH && x >= 0 && x < WW)
            idx = tab[((c.x * DD + z) * HH + y) * WW + x];
        nbr[k * NV + i] = idx;
        k++;
    }
}

// ---- layer 1: cin=1, fp32 VALU, fused BN+ReLU, write f16 x1 ----
__global__ void k_layer1(const float* __restrict__ feats, const int* __restrict__ nbr,
                         const float* __restrict__ w1, const float* __restrict__ b1,
                         const float* __restrict__ g1, const float* __restrict__ be1,
                         const float* __restrict__ m1, const float* __restrict__ v1,
                         f16* __restrict__ x1) {
    int t = blockIdx.x * 256 + threadIdx.x;
    int i = t >> 6, c = t & 63;
    if (i >= NV) return;
    float acc = 0.f;
    #pragma unroll
    for (int k = 0; k < KOFF; k++) {
        int idx = nbr[k * NV + i];
        float f = (idx >= 0) ? feats[idx] : 0.f;
        acc += f * w1[k * CD + c];
    }
    float sc = g1[c] * rsqrtf(v1[c] + EPSV);
    float y = (acc + b1[c] - m1[c]) * sc + be1[c];
    x1[(size_t)i * CD + c] = (f16)fmaxf(y, 0.f);
}

// ---- conv layers 2/3: gather-implicit-GEMM with 32x32x16 f16 MFMA ----
// block: 256 threads (4 waves), 256 voxels; wave w: voxels [w*64, w*64+64) x 64 cout.
// LDS feat tile: 256 rows x 128B, chunk-swizzled: chunk c of row v at v*128+((c+v)&7)*16
// LDS weight tile: 64 rows (cout) x 128B, same swizzle.
template <bool OUTF32>
__global__ __launch_bounds__(256, 2) void k_conv(
        const f16* __restrict__ xin, const f16* __restrict__ wT,
        const int* __restrict__ nbr, const f16* __restrict__ zrow,
        const float* __restrict__ bb, const float* __restrict__ gg,
        const float* __restrict__ bee, const float* __restrict__ mm,
        const float* __restrict__ vv, void* __restrict__ outp) {
    __shared__ __align__(16) unsigned char sA[256 * 128];  // 32 KB
    __shared__ __align__(16) unsigned char sB[CD * 128];   // 8 KB

    const int tid = threadIdx.x;
    const int lane = tid & 63;
    const int wv = tid >> 6;
    const int g = lane >> 5;     // k-group within MFMA (0/1)
    const int ml = lane & 31;
    const long vbase = (long)blockIdx.x * 256;

    f32x16 acc[2][2];
    #pragma unroll
    for (int a = 0; a < 2; a++)
        #pragma unroll
        for (int b = 0; b < 2; b++) acc[a][b] = (f32x16)(0.f);

    #pragma unroll 1
    for (int k = 0; k < KOFF; k++) {
        __syncthreads();  // prior iter's ds_reads done before LDS overwrite
        // stage features: 256 rows x 8 chunks = 2048 slots, 8 iters of 256 lanes
        #pragma unroll
        for (int it = 0; it < 8; it++) {
            int s = it * 256 + tid;
            int v = s >> 3, j = s & 7;
            int ch = (j - v) & 7;
            long gi = vbase + v;
            int idx = (gi < NV) ? nbr[(size_t)k * NV + gi] : -1;
            const char* gp = (idx >= 0)
                ? ((const char*)xin + ((size_t)idx * 128 + ch * 16))
                : ((const char*)zrow + ch * 16);
            char* lp = (char*)sA + it * 4096 + wv * 1024;  // wave-uniform base
            GLDS16(gp, lp);
        }
        // stage weights for offset k: 64 rows x 8 chunks = 512 slots, 2 iters
        #pragma unroll
        for (int it = 0; it < 2; it++) {
            int s = it * 256 + tid;
            int n = s >> 3, j = s & 7;
            int ch = (j - n) & 7;
            const char* gp = (const char*)wT + ((size_t)k * 8192 + n * 128 + ch * 16);
            char* lp = (char*)sB + it * 4096 + wv * 1024;
            GLDS16(gp, lp);
        }
        __syncthreads();  // drains vmcnt: staged data visible
        // compute: 4 k-steps of 16 over the 64 input channels
        #pragma unroll
        for (int ks = 0; ks < 4; ks++) {
            int chunk = ks * 2 + g;
            f16x8 afr[2], bfr[2];
            #pragma unroll
            for (int vt = 0; vt < 2; vt++) {
                int vrow = wv * 64 + vt * 32 + ml;   // A[m=lane&31][k=g*8+j]
                afr[vt] = *(const f16x8*)(sA + vrow * 128 + ((chunk + vrow) & 7) * 16);
            }
            #pragma unroll
            for (int nt = 0; nt < 2; nt++) {
                int nrow = nt * 32 + ml;             // B[k=g*8+j][n=lane&31]
                bfr[nt] = *(const f16x8*)(sB + nrow * 128 + ((chunk + nrow) & 7) * 16);
            }
            #pragma unroll
            for (int vt = 0; vt < 2; vt++)
                #pragma unroll
                for (int nt = 0; nt < 2; nt++)
                    acc[vt][nt] = __builtin_amdgcn_mfma_f32_32x32x16_f16(
                        afr[vt], bfr[nt], acc[vt][nt], 0, 0, 0);
        }
    }

    // epilogue: bias + BN + ReLU, store. C/D: col=lane&31, row=(r&3)+8*(r>>2)+4*(lane>>5)
    const long gib = vbase + wv * 64;
    #pragma unroll
    for (int nt = 0; nt < 2; nt++) {
        int cn = nt * 32 + ml;
        float sc = gg[cn] * rsqrtf(vv[cn] + EPSV);
        float sh = (bb[cn] - mm[cn]) * sc + bee[cn];
        #pragma unroll
        for (int vt = 0; vt < 2; vt++) {
            #pragma unroll
            for (int r = 0; r < 16; r++) {
                int row = (r & 3) + 8 * (r >> 2) + 4 * g;
                long gi = gib + vt * 32 + row;
                if (gi < NV) {
                    float y = fmaxf(acc[vt][nt][r] * sc + sh, 0.f);
                    if (OUTF32) ((float*)outp)[gi * 64 + cn] = y;
                    else        ((f16*)outp)[gi * 64 + cn] = (f16)y;
                }
            }
        }
    }
}

extern "C" void kernel_launch(void* const* d_in, const int* in_sizes, int n_in,
                              void* d_out, int out_size, void* d_ws, size_t ws_size,
                              hipStream_t stream) {
    (void)in_sizes; (void)n_in; (void)out_size; (void)ws_size;
    const float* feats = (const float*)d_in[0];
    const int4* coords = (const int4*)d_in[1];
    const float* w1 = (const float*)d_in[2];
    const float* b1 = (const float*)d_in[3];
    const float* g1 = (const float*)d_in[4];
    const float* be1 = (const float*)d_in[5];
    const float* m1 = (const float*)d_in[6];
    const float* v1 = (const float*)d_in[7];
    const float* w2 = (const float*)d_in[8];
    const float* b2 = (const float*)d_in[9];
    const float* g2 = (const float*)d_in[10];
    const float* be2 = (const float*)d_in[11];
    const float* m2 = (const float*)d_in[12];
    const float* v2 = (const float*)d_in[13];
    const float* w3 = (const float*)d_in[14];
    const float* b3 = (const float*)d_in[15];
    const float* g3 = (const float*)d_in[16];
    const float* be3 = (const float*)d_in[17];
    const float* m3 = (const float*)d_in[18];
    const float* v3 = (const float*)d_in[19];

    char* ws = (char*)d_ws;
    int* nbr  = (int*)(ws + OFF_NBR);
    f16* x1   = (f16*)(ws + OFF_X1);
    f16* x2   = (f16*)(ws + OFF_X2);
    int* tab  = (int*)(ws + OFF_TAB);
    f16* w2t  = (f16*)(ws + OFF_W2T);
    f16* w3t  = (f16*)(ws + OFF_W3T);
    f16* zrow = (f16*)(ws + OFF_ZERO);

    k_init<<<4096, 256, 0, stream>>>(w2, w3, tab, w2t, w3t, zrow);
    k_scatter<<<(NV + 255) / 256, 256, 0, stream>>>(coords, tab);
    k_nbr<<<(NV + 255) / 256, 256, 0, stream>>>(coords, tab, nbr);
    k_layer1<<<(NV * CD + 255) / 256, 256, 0, stream>>>(feats, nbr, w1, b1, g1, be1, m1, v1, x1);
    const int convgrid = (NV + 255) / 256;  // 1563
    k_conv<false><<<convgrid, 256, 0, stream>>>(x1, w2t, nbr, zrow, b2, g2, be2, m2, v2, (void*)x2);
    k_conv<true><<<convgrid, 256, 0, stream>>>(x2, w3t, nbr, zrow, b3, g3, be3, m3, v3, d_out);
}

// Round 2
// 537.949 us; speedup vs baseline: 2.4112x; 2.4112x over previous
//
#include <hip/hip_runtime.h>

#define NV 400000
#define KOFF 27
#define CD 64
#define DD 128
#define HH 128
#define WW 128
#define TABN (2*DD*HH*WW)
#define EPSV 1e-5f

typedef _Float16 f16;
typedef _Float16 f16x8 __attribute__((ext_vector_type(8)));
typedef float f32x16 __attribute__((ext_vector_type(16)));

// ---- workspace layout (bytes) ----
#define OFF_NBR   0ull
#define OFF_X1    43200000ull
#define OFF_X2    94400000ull
#define OFF_TAB   94400000ull     // table dead before x2 written
#define OFF_W2T   145600000ull
#define OFF_W3T   145821184ull
#define OFF_ZERO  146042368ull

#define GLDS16(gp, lp) __builtin_amdgcn_global_load_lds( \
    (__attribute__((address_space(1))) void*)(gp), \
    (__attribute__((address_space(3))) void*)(lp), 16, 0, 0)

// ---- init: table = -1, transpose+cast weights to f16 [k][cout][cin], zero row ----
__global__ void k_init(const float* __restrict__ w2, const float* __restrict__ w3,
                       int* __restrict__ tab, f16* __restrict__ w2t,
                       f16* __restrict__ w3t, f16* __restrict__ zrow) {
    int t = blockIdx.x * 256 + threadIdx.x;           // grid: 4096*256
    int4* tv = (int4*)tab;
    if (t < TABN / 4) tv[t] = make_int4(-1, -1, -1, -1);
    if (t < KOFF * CD * CD) {
        int k = t >> 12, r = t & 4095, c = r >> 6, ci = r & 63;
        w2t[t] = (f16)w2[(k << 12) + (ci << 6) + c];
        w3t[t] = (f16)w3[(k << 12) + (ci << 6) + c];
    }
    if (t < CD) zrow[t] = (f16)0.f;
}

__global__ void k_scatter(const int4* __restrict__ coords, int* __restrict__ tab) {
    int i = blockIdx.x * 256 + threadIdx.x;
    if (i >= NV) return;
    int4 c = coords[i];  // (b,z,y,x)
    int flat = ((c.x * DD + c.y) * HH + c.z) * WW + c.w;
    tab[flat] = i;
}

__global__ void k_nbr(const int4* __restrict__ coords, const int* __restrict__ tab,
                      int* __restrict__ nbr) {
    int i = blockIdx.x * 256 + threadIdx.x;
    if (i >= NV) return;
    int4 c = coords[i];
    int k = 0;
    #pragma unroll
    for (int dz = -1; dz <= 1; dz++)
    #pragma unroll
    for (int dy = -1; dy <= 1; dy++)
    #pragma unroll
    for (int dx = -1; dx <= 1; dx++) {
        int z = c.y + dz, y = c.z + dy, x = c.w + dx;
        int idx = -1;
        if (z >= 0 && z < DD && y >= 0 && y < HH && x >= 0 && x < WW)
            idx = tab[((c.x * DD + z) * HH + y) * WW + x];
        nbr[k * NV + i] = idx;
        k++;
    }
}

// ---- layer 1 v2: one thread per voxel. 27 gathers -> acc[64] in VGPRs,
// weights via wave-uniform loads (scalarized), fused BN+ReLU, 16B stores.
__global__ __launch_bounds__(256) void k_layer1(
        const float* __restrict__ feats, const int* __restrict__ nbr,
        const float* __restrict__ w1, const float* __restrict__ b1,
        const float* __restrict__ g1, const float* __restrict__ be1,
        const float* __restrict__ m1, const float* __restrict__ v1,
        f16* __restrict__ x1) {
    int i = blockIdx.x * 256 + threadIdx.x;
    bool act = (i < NV);
    int ii = act ? i : 0;

    float acc[CD];
    #pragma unroll
    for (int c = 0; c < CD; c++) acc[c] = 0.f;

    #pragma unroll
    for (int k = 0; k < KOFF; k++) {
        int idx = act ? nbr[k * NV + ii] : -1;
        float fk = (idx >= 0) ? feats[idx] : 0.f;
        #pragma unroll
        for (int c = 0; c < CD; c++)
            acc[c] = fmaf(fk, w1[k * CD + c], acc[c]);  // w1 addr wave-uniform -> s_load
    }
    if (!act) return;

    #pragma unroll
    for (int c0 = 0; c0 < CD; c0 += 8) {
        f16x8 o;
        #pragma unroll
        for (int j = 0; j < 8; j++) {
            int c = c0 + j;
            float sc = g1[c] * rsqrtf(v1[c] + EPSV);
            float y = (acc[c] - m1[c] + b1[c]) * sc + be1[c];
            o[j] = (f16)fmaxf(y, 0.f);
        }
        *(f16x8*)(x1 + (size_t)i * CD + c0) = o;
    }
}

// ---- conv v2: A-frags gathered per-lane straight from global (no LDS for A);
// B (8KB weight tile) in LDS, double-buffered, one barrier per k.
// block: 256 threads / 4 waves / 256 voxels; wave: 64 vox x 64 cout.
template <bool OUTF32>
__global__ __launch_bounds__(256, 3) void k_conv(
        const f16* __restrict__ xin, const f16* __restrict__ wT,
        const int* __restrict__ nbr, const f16* __restrict__ zrow,
        const float* __restrict__ bb, const float* __restrict__ gg,
        const float* __restrict__ bee, const float* __restrict__ mm,
        const float* __restrict__ vv, void* __restrict__ outp) {
    __shared__ __align__(16) unsigned char sB[2][8192];

    const int tid = threadIdx.x;
    const int lane = tid & 63;
    const int wv = tid >> 6;
    const int g = lane >> 5;     // k-group within MFMA (0/1)
    const int ml = lane & 31;
    const long vbase = (long)blockIdx.x * 256;

    f32x16 acc[2][2];
    #pragma unroll
    for (int a = 0; a < 2; a++)
        #pragma unroll
        for (int b = 0; b < 2; b++) acc[a][b] = (f32x16)(0.f);

    // prologue: stage weight tile k=0 into buffer 0
    #pragma unroll
    for (int it = 0; it < 2; it++) {
        int s = it * 256 + tid;
        int n = s >> 3, j = s & 7;
        int ch = (j - n) & 7;
        const char* gp = (const char*)wT + (n * 128 + ch * 16);
        char* lp = (char*)sB[0] + it * 4096 + wv * 1024;
        GLDS16(gp, lp);
    }

    #pragma unroll 1
    for (int k = 0; k < KOFF; k++) {
        __syncthreads();  // drains vmcnt: B(k) staged; prior reads of other buf done
        if (k + 1 < KOFF) {
            #pragma unroll
            for (int it = 0; it < 2; it++) {
                int s = it * 256 + tid;
                int n = s >> 3, j = s & 7;
                int ch = (j - n) & 7;
                const char* gp = (const char*)wT + ((size_t)(k + 1) * 8192 + n * 128 + ch * 16);
                char* lp = (char*)sB[(k + 1) & 1] + it * 4096 + wv * 1024;
                GLDS16(gp, lp);
            }
        }
        // gather A-fragments straight to VGPRs: lane ml = voxel row, 16B chunks
        f16x8 afr[2][4];
        #pragma unroll
        for (int vt = 0; vt < 2; vt++) {
            long row = vbase + wv * 64 + vt * 32 + ml;
            int idx = (row < NV) ? nbr[(size_t)k * NV + row] : -1;
            const char* ap = (idx >= 0) ? (const char*)xin + (size_t)idx * 128
                                        : (const char*)zrow;
            ap += g * 16;
            #pragma unroll
            for (int ks = 0; ks < 4; ks++)
                afr[vt][ks] = *(const f16x8*)(ap + ks * 32);   // chunk ks*2+g
        }
        const unsigned char* bbuf = sB[k & 1];
        #pragma unroll
        for (int ks = 0; ks < 4; ks++) {
            int chunk = ks * 2 + g;
            f16x8 bfr[2];
            #pragma unroll
            for (int nt = 0; nt < 2; nt++) {
                int n = nt * 32 + ml;
                bfr[nt] = *(const f16x8*)(bbuf + n * 128 + ((chunk + n) & 7) * 16);
            }
            #pragma unroll
            for (int vt = 0; vt < 2; vt++)
                #pragma unroll
                for (int nt = 0; nt < 2; nt++)
                    acc[vt][nt] = __builtin_amdgcn_mfma_f32_32x32x16_f16(
                        afr[vt][ks], bfr[nt], acc[vt][nt], 0, 0, 0);
        }
    }

    // epilogue: BN+ReLU, store. C/D: col=lane&31, row=(r&3)+8*(r>>2)+4*(lane>>5)
    const long gib = vbase + wv * 64;
    #pragma unroll
    for (int nt = 0; nt < 2; nt++) {
        int cn = nt * 32 + ml;
        float sc = gg[cn] * rsqrtf(vv[cn] + EPSV);
        float sh = (bb[cn] - mm[cn]) * sc + bee[cn];
        #pragma unroll
        for (int vt = 0; vt < 2; vt++) {
            #pragma unroll
            for (int r = 0; r < 16; r++) {
                int row = (r & 3) + 8 * (r >> 2) + 4 * g;
                long gi = gib + vt * 32 + row;
                if (gi < NV) {
                    float y = fmaxf(acc[vt][nt][r] * sc + sh, 0.f);
                    if (OUTF32) ((float*)outp)[gi * 64 + cn] = y;
                    else        ((f16*)outp)[gi * 64 + cn] = (f16)y;
                }
            }
        }
    }
}

extern "C" void kernel_launch(void* const* d_in, const int* in_sizes, int n_in,
                              void* d_out, int out_size, void* d_ws, size_t ws_size,
                              hipStream_t stream) {
    (void)in_sizes; (void)n_in; (void)out_size; (void)ws_size;
    const float* feats = (const float*)d_in[0];
    const int4* coords = (const int4*)d_in[1];
    const float* w1 = (const float*)d_in[2];
    const float* b1 = (const float*)d_in[3];
    const float* g1 = (const float*)d_in[4];
    const float* be1 = (const float*)d_in[5];
    const float* m1 = (const float*)d_in[6];
    const float* v1 = (const float*)d_in[7];
    const float* w2 = (const float*)d_in[8];
    const float* b2 = (const float*)d_in[9];
    const float* g2 = (const float*)d_in[10];
    const float* be2 = (const float*)d_in[11];
    const float* m2 = (const float*)d_in[12];
    const float* v2 = (const float*)d_in[13];
    const float* w3 = (const float*)d_in[14];
    const float* b3 = (const float*)d_in[15];
    const float* g3 = (const float*)d_in[16];
    const float* be3 = (const float*)d_in[17];
    const float* m3 = (const float*)d_in[18];
    const float* v3 = (const float*)d_in[19];

    char* ws = (char*)d_ws;
    int* nbr  = (int*)(ws + OFF_NBR);
    f16* x1   = (f16*)(ws + OFF_X1);
    f16* x2   = (f16*)(ws + OFF_X2);
    int* tab  = (int*)(ws + OFF_TAB);
    f16* w2t  = (f16*)(ws + OFF_W2T);
    f16* w3t  = (f16*)(ws + OFF_W3T);
    f16* zrow = (f16*)(ws + OFF_ZERO);

    k_init<<<4096, 256, 0, stream>>>(w2, w3, tab, w2t, w3t, zrow);
    k_scatter<<<(NV + 255) / 256, 256, 0, stream>>>(coords, tab);
    k_nbr<<<(NV + 255) / 256, 256, 0, stream>>>(coords, tab, nbr);
    k_layer1<<<(NV + 255) / 256, 256, 0, stream>>>(feats, nbr, w1, b1, g1, be1, m1, v1, x1);
    const int convgrid = (NV + 255) / 256;  // 1563
    k_conv<false><<<convgrid, 256, 0, stream>>>(x1, w2t, nbr, zrow, b2, g2, be2, m2, v2, (void*)x2);
    k_conv<true><<<convgrid, 256, 0, stream>>>(x2, w3t, nbr, zrow, b3, g3, be3, m3, v3, d_out);
}